// Round 1
// baseline (195.511 us; speedup 1.0000x reference)
//
#include <hip/hip_runtime.h>
#include <math.h>

// Tropical (max-plus) depthwise 3x3 conv, stride=1, pad=1, dil=1.
// x: (B=8, C=64, H=224, W=224) fp32; kernel: (64,1,3,3) fp32; out = x shape.
//
// R2 design: one thread -> 16 output rows x 1 float4, via a rolling 4-slot
// register window over input rows.
//   - 18 row-loads per 16 output rows (1.125x read amplification, vs 1.5x
//     for the previous 4-row tiling whose inter-group overlap was re-fetched
//     from HBM because adjacent blocks land on different XCDs),
//   - next input row prefetched one iteration ahead (slot (o+3)&3), fully
//     unrolled so all ring indices are compile-time constants (no scratch),
//   - coalesced: consecutive lanes -> consecutive float4 in the same row;
//     halo scalars hit the same cache lines as neighbor lanes' float4s.

#define H_DIM 224
#define W_DIM 224
#define W4    56            // W/4
#define ROWS  16            // output rows per thread
#define GR    14            // H/ROWS row-groups
#define C_DIM 64

__global__ __launch_bounds__(256) void tropical_conv_kernel(
    const float* __restrict__ x,
    const float* __restrict__ kern,
    float* __restrict__ out,
    int total)   // total threads = B*C*GR*W4
{
    int idx = blockIdx.x * blockDim.x + threadIdx.x;
    if (idx >= total) return;

    const float NEG = -INFINITY;

    int j4 = idx % W4;          // float4 index within the row
    int t  = idx / W4;
    int g  = t % GR;            // 16-row group
    int bc = t / GR;            // fused batch*channel plane
    int c  = bc & (C_DIM - 1);

    const float* kc = kern + c * 9;
    float k00 = kc[0], k01 = kc[1], k02 = kc[2];
    float k10 = kc[3], k11 = kc[4], k12 = kc[5];
    float k20 = kc[6], k21 = kc[7], k22 = kc[8];

    const float* plane  = x   + (size_t)bc * (H_DIM * W_DIM);
    float*       oplane = out + (size_t)bc * (H_DIM * W_DIM);
    int j0 = j4 * 4;
    int i0 = g * ROWS;

    // Rolling 4-slot ring of input rows. Invariant entering iteration o:
    // slot (o+k)&3 holds input row i0-1+o+k for k=0..2.
    float4 rv[4];
    float  lf[4], rg[4];

#define LOADROW(s, r) do {                                           \
        int _r = (r);                                                \
        if (_r >= 0 && _r < H_DIM) {                                 \
            const float* _row = plane + _r * W_DIM;                  \
            rv[s] = *(const float4*)(_row + j0);                     \
            lf[s] = (j4 > 0)      ? _row[j0 - 1] : NEG;              \
            rg[s] = (j4 < W4 - 1) ? _row[j0 + 4] : NEG;              \
        } else {                                                     \
            rv[s] = make_float4(NEG, NEG, NEG, NEG);                 \
            lf[s] = NEG;                                             \
            rg[s] = NEG;                                             \
        }                                                            \
    } while (0)

    LOADROW(0, i0 - 1);
    LOADROW(1, i0);
    LOADROW(2, i0 + 1);

    #pragma unroll
    for (int o = 0; o < ROWS; ++o) {
        // Prefetch row i0+o+2 into slot (o+3)&3 (consumed next iteration).
        // Last iteration needs nothing beyond row i0+16 (loaded at o=14).
        if (o < ROWS - 1) {
            LOADROW((o + 3) & 3, i0 + o + 2);
        }

        float4 acc = make_float4(NEG, NEG, NEG, NEG);
        #pragma unroll
        for (int ki = 0; ki < 3; ++ki) {
            int s = (o + ki) & 3;       // compile-time constant after unroll
            float t0 = (ki == 0) ? k00 : (ki == 1) ? k10 : k20;
            float t1 = (ki == 0) ? k01 : (ki == 1) ? k11 : k21;
            float t2 = (ki == 0) ? k02 : (ki == 1) ? k12 : k22;
            float4 a = rv[s];
            acc.x = fmaxf(acc.x, fmaxf(fmaxf(lf[s] + t0, a.x + t1), a.y   + t2));
            acc.y = fmaxf(acc.y, fmaxf(fmaxf(a.x   + t0, a.y + t1), a.z   + t2));
            acc.z = fmaxf(acc.z, fmaxf(fmaxf(a.y   + t0, a.z + t1), a.w   + t2));
            acc.w = fmaxf(acc.w, fmaxf(fmaxf(a.z   + t0, a.w + t1), rg[s] + t2));
        }
        *(float4*)(oplane + (size_t)(i0 + o) * W_DIM + j0) = acc;
    }
#undef LOADROW
}

extern "C" void kernel_launch(void* const* d_in, const int* in_sizes, int n_in,
                              void* d_out, int out_size, void* d_ws, size_t ws_size,
                              hipStream_t stream) {
    const float* x    = (const float*)d_in[0];
    const float* kern = (const float*)d_in[1];
    float* out        = (float*)d_out;

    const int total = 8 * C_DIM * GR * W4;   // 458,752 threads
    const int block = 256;
    const int grid  = (total + block - 1) / block;  // 1792 blocks
    tropical_conv_kernel<<<grid, block, 0, stream>>>(x, kern, out, total);
}

// Round 5
// 188.736 us; speedup vs baseline: 1.0359x; 1.0359x over previous
//
#include <hip/hip_runtime.h>
#include <math.h>

// Tropical (max-plus) depthwise 3x3 conv, stride=1, pad=1, dil=1.
// x: (B=8, C=64, H=224, W=224) fp32; kernel: (64,1,3,3) fp32; out = x shape.
//
// R6 = R3 design with plain float4 stores (dropped the nontemporal-store
// builtin — two consecutive container failures on that source; removing
// the only harness-unvalidated construct).
//
// R3 design: one thread -> 8 output rows x 1 float4; ALL 10 input rows
// loaded up-front as independent loads (batch MLP, ~11 KB in flight per
// wave) — R2's rolling window (prefetch distance 1) was latency-exposed
// (VALUBusy 15%, HBM 30%). Lessons: L3 absorbs vertical re-reads (FETCH
// 59MB < input 103MB), so amplification is cheap; in-flight bytes are
// what matter.
//   + XCD-aware block swizzle: adjacent row-groups (2-row halo overlap)
//     land on the same XCD -> halo re-reads hit that XCD's L2.

#define H_DIM 224
#define W_DIM 224
#define W4    56            // W/4
#define ROWS  8             // output rows per thread
#define GR    28            // H/ROWS row-groups
#define C_DIM 64
#define NXCD  8

__global__ __launch_bounds__(256) void tropical_conv_kernel(
    const float* __restrict__ x,
    const float* __restrict__ kern,
    float* __restrict__ out,
    int total)   // total threads = B*C*GR*W4 = 802,816 (grid 3136 blocks)
{
    // XCD-aware swizzle: grid (3136) is divisible by 8, so this is bijective.
    // Consecutive swizzled blocks (same XCD) cover adjacent row-groups of the
    // same plane -> halo rows are L2-local.
    int bid  = blockIdx.x;
    int cpx  = gridDim.x >> 3;                 // blocks per XCD chunk
    int swz  = (bid & (NXCD - 1)) * cpx + (bid >> 3);
    int idx  = swz * blockDim.x + threadIdx.x;
    if (idx >= total) return;

    const float NEG = -INFINITY;

    int j4 = idx % W4;          // float4 index within the row
    int t  = idx / W4;
    int g  = t % GR;            // 8-row group
    int bc = t / GR;            // fused batch*channel plane
    int c  = bc & (C_DIM - 1);

    const float* kc = kern + c * 9;
    float k00 = kc[0], k01 = kc[1], k02 = kc[2];
    float k10 = kc[3], k11 = kc[4], k12 = kc[5];
    float k20 = kc[6], k21 = kc[7], k22 = kc[8];

    const float* plane  = x   + (size_t)bc * (H_DIM * W_DIM);
    float*       oplane = out + (size_t)bc * (H_DIM * W_DIM);
    int j0 = j4 * 4;
    int i0 = g * ROWS;

    // Load all 10 input rows (i0-1 .. i0+8) with horizontal halos, up front.
    // 30 independent memory instructions -> deep MLP before any compute.
    float4 rv[ROWS + 2];
    float  lf[ROWS + 2], rg[ROWS + 2];
    #pragma unroll
    for (int rr = 0; rr < ROWS + 2; ++rr) {
        int r = i0 - 1 + rr;
        if (r >= 0 && r < H_DIM) {
            const float* row = plane + r * W_DIM;
            rv[rr] = *(const float4*)(row + j0);
            lf[rr] = (j4 > 0)      ? row[j0 - 1] : NEG;
            rg[rr] = (j4 < W4 - 1) ? row[j0 + 4] : NEG;
        } else {
            rv[rr] = make_float4(NEG, NEG, NEG, NEG);
            lf[rr] = NEG;
            rg[rr] = NEG;
        }
    }

    #pragma unroll
    for (int o = 0; o < ROWS; ++o) {
        float4 acc = make_float4(NEG, NEG, NEG, NEG);
        #pragma unroll
        for (int ki = 0; ki < 3; ++ki) {
            int rr = o + ki;            // compile-time constant after unroll
            float t0 = (ki == 0) ? k00 : (ki == 1) ? k10 : k20;
            float t1 = (ki == 0) ? k01 : (ki == 1) ? k11 : k21;
            float t2 = (ki == 0) ? k02 : (ki == 1) ? k12 : k22;
            float4 a = rv[rr];
            acc.x = fmaxf(acc.x, fmaxf(fmaxf(lf[rr] + t0, a.x + t1), a.y    + t2));
            acc.y = fmaxf(acc.y, fmaxf(fmaxf(a.x    + t0, a.y + t1), a.z    + t2));
            acc.z = fmaxf(acc.z, fmaxf(fmaxf(a.y    + t0, a.z + t1), a.w    + t2));
            acc.w = fmaxf(acc.w, fmaxf(fmaxf(a.z    + t0, a.w + t1), rg[rr] + t2));
        }
        *(float4*)(oplane + (size_t)(i0 + o) * W_DIM + j0) = acc;
    }
}

extern "C" void kernel_launch(void* const* d_in, const int* in_sizes, int n_in,
                              void* d_out, int out_size, void* d_ws, size_t ws_size,
                              hipStream_t stream) {
    const float* x    = (const float*)d_in[0];
    const float* kern = (const float*)d_in[1];
    float* out        = (float*)d_out;

    const int total = 8 * C_DIM * GR * W4;   // 802,816 threads
    const int block = 256;
    const int grid  = (total + block - 1) / block;  // 3136 blocks (8 x 392)
    tropical_conv_kernel<<<grid, block, 0, stream>>>(x, kern, out, total);
}